// Round 8
// baseline (566.440 us; speedup 1.0000x reference)
//
#include <hip/hip_runtime.h>
#include <math.h>

// Problem constants
#define BB 128
#define TT 256
#define NN 64
#define OO 32
#define EE 32
#define HH 64
#define SS 129
#define BT 32768      // B*T
#define SP 132        // padded state pitch (multiple of 4)

#define SHFLR_ADD(v, off) { v.x += __shfl_xor(v.x, off); v.y += __shfl_xor(v.y, off); \
                            v.z += __shfl_xor(v.z, off); v.w += __shfl_xor(v.w, off); }
#define SHFLR_MIN(v, off) { v.x = fminf(v.x, __shfl_xor(v.x, off)); v.y = fminf(v.y, __shfl_xor(v.y, off)); \
                            v.z = fminf(v.z, __shfl_xor(v.z, off)); v.w = fminf(v.w, __shfl_xor(v.w, off)); }
#define SHFLR_MAX(v, off) { v.x = fmaxf(v.x, __shfl_xor(v.x, off)); v.y = fmaxf(v.y, __shfl_xor(v.y, off)); \
                            v.z = fmaxf(v.z, __shfl_xor(v.z, off)); v.w = fmaxf(v.w, __shfl_xor(v.w, off)); }

// ---------------------------------------------------------------------------
// Kernel A v2: state features. One wave per (b,t) row.
// lane l: o-chunk og=(l&7)*4 (float4), agent subgroup ng=l>>3.
// Per iteration the wave loads 8 agents x 32 obs = 1 KB in ONE coalesced
// float4 instruction; loads are independent (no per-iter vmcnt serialization).
// Count-adaptive: blocks of 8 agents beyond k are skipped entirely.
// ---------------------------------------------------------------------------
__global__ __launch_bounds__(256) void k_states(const float* __restrict__ obs,
                                                const int* __restrict__ mask,
                                                float* __restrict__ states) {
    int w = threadIdx.x >> 6;
    int l = threadIdx.x & 63;
    int bt = blockIdx.x * 4 + w;
    int b = bt >> 8;   // T = 256

    // k = number of active agents for this batch row (count-based mask)
    int kv = mask[(b << 6) + l];
    #pragma unroll
    for (int off = 32; off; off >>= 1) kv += __shfl_xor(kv, off);

    int og = (l & 7) * 4;   // obs feature base (float4)
    int ng = l >> 3;        // agent subgroup 0..7
    float4 s  = make_float4(0.f, 0.f, 0.f, 0.f);
    float4 sq = make_float4(0.f, 0.f, 0.f, 0.f);
    float4 mn = make_float4(INFINITY, INFINITY, INFINITY, INFINITY);
    float4 mx = make_float4(-INFINITY, -INFINITY, -INFINITY, -INFINITY);
    const float* op = obs + ((size_t)bt << 11);   // bt * N * O

    for (int nb = 0; nb < kv; nb += 8) {
        int n = nb + ng;                           // <= 63 always (nb <= 56)
        float4 v = *(const float4*)(op + (n << 5) + og);
        if (n < kv) {
            s.x += v.x; s.y += v.y; s.z += v.z; s.w += v.w;
            sq.x = fmaf(v.x, v.x, sq.x); sq.y = fmaf(v.y, v.y, sq.y);
            sq.z = fmaf(v.z, v.z, sq.z); sq.w = fmaf(v.w, v.w, sq.w);
            mn.x = fminf(mn.x, v.x); mn.y = fminf(mn.y, v.y);
            mn.z = fminf(mn.z, v.z); mn.w = fminf(mn.w, v.w);
            mx.x = fmaxf(mx.x, v.x); mx.y = fmaxf(mx.y, v.y);
            mx.z = fmaxf(mx.z, v.z); mx.w = fmaxf(mx.w, v.w);
        }
    }

    // reduce across the 8 agent subgroups (lane bits 3,4,5)
    SHFLR_ADD(s, 8)  SHFLR_ADD(s, 16)  SHFLR_ADD(s, 32)
    SHFLR_ADD(sq, 8) SHFLR_ADD(sq, 16) SHFLR_ADD(sq, 32)
    SHFLR_MIN(mn, 8) SHFLR_MIN(mn, 16) SHFLR_MIN(mn, 32)
    SHFLR_MAX(mx, 8) SHFLR_MAX(mx, 16) SHFLR_MAX(mx, 32)

    float kf = (float)kv;
    float* sp = states + (size_t)bt * SP;
    if (l < 8) {
        float4 mean4, sd4;
        float inv = 1.f / fmaxf(kf, 1.f);
        float invv = 1.f / fmaxf(kf - 1.f, 1.f);
        mean4.x = s.x * inv; mean4.y = s.y * inv;
        mean4.z = s.z * inv; mean4.w = s.w * inv;
        if (kv > 1) {
            sd4.x = sqrtf(fmaxf((sq.x - kf * mean4.x * mean4.x) * invv, 0.f));
            sd4.y = sqrtf(fmaxf((sq.y - kf * mean4.y * mean4.y) * invv, 0.f));
            sd4.z = sqrtf(fmaxf((sq.z - kf * mean4.z * mean4.z) * invv, 0.f));
            sd4.w = sqrtf(fmaxf((sq.w - kf * mean4.w * mean4.w) * invv, 0.f));
        } else {
            sd4 = make_float4(0.f, 0.f, 0.f, 0.f);
        }
        if (kv == 0) {
            mean4 = make_float4(0.f, 0.f, 0.f, 0.f);
            mn = make_float4(0.f, 0.f, 0.f, 0.f);
            mx = make_float4(0.f, 0.f, 0.f, 0.f);
        }
        *(float4*)(sp + og)      = mean4;
        *(float4*)(sp + 32 + og) = sd4;
        *(float4*)(sp + 64 + og) = mn;
        *(float4*)(sp + 96 + og) = mx;
    }
    if (l == 0)
        *(float4*)(sp + 128) = make_float4(kf * 0.015625f, 0.f, 0.f, 0.f);
}

// ---------------------------------------------------------------------------
// Kernel B1 v2: K=129 GEMM: states(BT x 129) @ Whalf(129 x 96) + bias + act.
// Column halves (blockIdx.y): half0 = [w1_1(64)->h1 relu | wb1(32)->b1v none]
//                             half1 = [w2_1(64)->t2 relu | wb2_1(32)->t3 relu]
// 50 KB LDS -> 3 blocks/CU (3 waves/SIMD).
// 128 rows/block, 256 threads: 32 row-groups x 8 col-groups, 4x12 per thread.
// ---------------------------------------------------------------------------
__global__ __launch_bounds__(256, 3) void k_mlp1(const float* __restrict__ states,
        const float* __restrict__ w1_1, const float* __restrict__ b1_1,
        const float* __restrict__ w2_1, const float* __restrict__ b2_1,
        const float* __restrict__ wb1,  const float* __restrict__ bb1,
        const float* __restrict__ wb2_1,const float* __restrict__ bb2_1,
        float* __restrict__ h1, float* __restrict__ t2,
        float* __restrict__ b1v, float* __restrict__ t3) {
    __shared__ float wl[SP * 96];   // 50,688 B, zero-padded k=129..131
    __shared__ float bl[96];
    int t = threadIdx.x;
    int half = blockIdx.y;

    const float* wA = half ? w2_1 : w1_1;   // 129 x 64
    const float* wB = half ? wb2_1 : wb1;   // 129 x 32
    const float* bA = half ? b2_1 : b1_1;
    const float* bB = half ? bb2_1 : bb1;
    float* outA = half ? t2 : h1;           // pitch 64
    float* outB = half ? t3 : b1v;          // pitch 32
    int reluB = half;                       // b1v cols have no relu

    for (int idx = t; idx < SP * 96; idx += 256) {
        int k = idx / 96;
        int c = idx - k * 96;
        float v = 0.f;
        if (k < SS) v = (c < 64) ? wA[k * 64 + c] : wB[k * 32 + (c - 64)];
        wl[idx] = v;
    }
    if (t < 96) bl[t] = (t < 64) ? bA[t] : bB[t - 64];
    __syncthreads();

    int cg = t & 7, rg = t >> 3;
    int c0 = cg * 12;
    int row0 = blockIdx.x * 128 + rg * 4;
    float acc[4][12];
    #pragma unroll
    for (int i = 0; i < 4; i++)
        #pragma unroll
        for (int j = 0; j < 12; j++) acc[i][j] = 0.f;

    const float* s0 = states + (size_t)row0 * SP;
    for (int k0 = 0; k0 < SP; k0 += 4) {
        float sv[4][4];
        #pragma unroll
        for (int i = 0; i < 4; i++)
            *(float4*)&sv[i][0] = *(const float4*)(s0 + i * SP + k0);
        #pragma unroll
        for (int kk = 0; kk < 4; kk++) {
            float wv[12];
            #pragma unroll
            for (int q = 0; q < 3; q++)
                *(float4*)&wv[q * 4] = *(const float4*)&wl[(k0 + kk) * 96 + c0 + q * 4];
            #pragma unroll
            for (int i = 0; i < 4; i++) {
                float s = sv[i][kk];
                #pragma unroll
                for (int j = 0; j < 12; j++) acc[i][j] = fmaf(s, wv[j], acc[i][j]);
            }
        }
    }

    #pragma unroll
    for (int i = 0; i < 4; i++) {
        int row = row0 + i;
        #pragma unroll
        for (int j = 0; j < 12; j++) {
            int c = c0 + j;
            float v = acc[i][j] + bl[c];
            if (c < 64) {
                v = fmaxf(v, 0.f);
                outA[(size_t)row * 64 + c] = v;
            } else {
                if (reluB) v = fmaxf(v, 0.f);
                outB[(size_t)row * 32 + (c - 64)] = v;
            }
        }
    }
}

// ---------------------------------------------------------------------------
// Kernel B3: w2 = |t2 @ w2_2 + b2_2| (BTx32), b2v = t3 @ wb2_2 + bb2_2 (BT)
// 64 rows/block, 256 threads: 4 threads/row, 8 e-cols each.
// ---------------------------------------------------------------------------
__global__ __launch_bounds__(256) void k_w2(const float* __restrict__ t2,
        const float* __restrict__ t3, const float* __restrict__ w2_2,
        const float* __restrict__ b2_2, const float* __restrict__ wb2_2,
        const float* __restrict__ bb2_2,
        float* __restrict__ w2, float* __restrict__ b2v) {
    __shared__ float wl[64 * 32];
    __shared__ float wb[32];
    __shared__ float bb[32];
    int t = threadIdx.x;
    for (int idx = t; idx < 2048; idx += 256) wl[idx] = w2_2[idx];
    if (t < 32) wb[t] = wb2_2[t];
    if (t >= 32 && t < 64) bb[t - 32] = b2_2[t - 32];
    __syncthreads();

    int r = t >> 2, eq = t & 3;
    int row = blockIdx.x * 64 + r;
    int e0 = eq * 8;
    float acc[8];
    #pragma unroll
    for (int j = 0; j < 8; j++) acc[j] = 0.f;

    const float* tp = t2 + (size_t)row * 64;
    for (int h4 = 0; h4 < 64; h4 += 4) {
        float tv[4];
        *(float4*)tv = *(const float4*)(tp + h4);
        #pragma unroll
        for (int hh = 0; hh < 4; hh++) {
            float s = tv[hh];
            float4 wv0 = *(const float4*)&wl[(h4 + hh) * 32 + e0];
            float4 wv1 = *(const float4*)&wl[(h4 + hh) * 32 + e0 + 4];
            acc[0] = fmaf(s, wv0.x, acc[0]); acc[1] = fmaf(s, wv0.y, acc[1]);
            acc[2] = fmaf(s, wv0.z, acc[2]); acc[3] = fmaf(s, wv0.w, acc[3]);
            acc[4] = fmaf(s, wv1.x, acc[4]); acc[5] = fmaf(s, wv1.y, acc[5]);
            acc[6] = fmaf(s, wv1.z, acc[6]); acc[7] = fmaf(s, wv1.w, acc[7]);
        }
    }
    #pragma unroll
    for (int j = 0; j < 8; j++)
        w2[(size_t)row * 32 + e0 + j] = fabsf(acc[j] + bb[e0 + j]);

    if (eq == 0) {
        const float* t3p = t3 + (size_t)row * 32;
        float a = 0.f;
        #pragma unroll
        for (int q = 0; q < 8; q++) {
            float4 v3 = *(const float4*)(t3p + q * 4);
            float4 wv = *(const float4*)&wb[q * 4];
            a = fmaf(v3.x, wv.x, a); a = fmaf(v3.y, wv.y, a);
            a = fmaf(v3.z, wv.z, a); a = fmaf(v3.w, wv.w, a);
        }
        b2v[row] = a + bb2_2[0];
    }
}

// ---------------------------------------------------------------------------
// Kernel B2 v3: fused main GEMM + abs + qs-contraction + elu + w2-dot + out.
// 64 rows/block (512 blocks), 256 threads. Panels of 64 cols (2 n-values).
// T14 async-stage: panel p+1's W loads are issued into registers right after
// panel p's LDS-write barrier; the vmcnt wait lands after compute(p) -> HBM
// latency hidden under the 64-step FMA phase.
// C-tile 4x4, hacc 4x4, wreg 4xfloat4 -> ~96 VGPR. LDS 40 KB -> 4 blocks/CU.
// ---------------------------------------------------------------------------
__global__ __launch_bounds__(256, 4) void k_main(
        const float* __restrict__ h1g, const float* __restrict__ qsg,
        const float* __restrict__ w12, const float* __restrict__ b12,
        const float* __restrict__ b1vg, const float* __restrict__ w2g,
        const float* __restrict__ b2vg, float* __restrict__ out) {
    __shared__ float h1T[64 * 64];    // [h][row] 16 KB
    __shared__ float Wp[64 * 64];     // [h][panel-col] 16 KB
    __shared__ float hid[64 * 32];    // 8 KB
    int t = threadIdx.x;
    int row0 = blockIdx.x * 64;

    // stage h1 transposed: thread r=t>>2, h0=(t&3)*16, 16 scalar LDS writes
    {
        int r = t >> 2, h0 = (t & 3) * 16;
        const float* hp = h1g + (size_t)(row0 + r) * 64 + h0;
        #pragma unroll
        for (int q = 0; q < 4; q++) {
            float4 hv = *(const float4*)(hp + q * 4);
            int hb = h0 + q * 4;
            h1T[(hb + 0) * 64 + r] = hv.x;
            h1T[(hb + 1) * 64 + r] = hv.y;
            h1T[(hb + 2) * 64 + r] = hv.z;
            h1T[(hb + 3) * 64 + r] = hv.w;
        }
    }

    int rg = t >> 4, cg = t & 15;
    int n_l = cg >> 3;
    int e0 = (cg & 7) * 4;
    int r0 = rg * 4;
    int jcol = n_l * 32 + e0;

    int hs = t >> 4, c4 = (t & 15) * 4;       // W staging coords
    const float* wbase = w12 + (size_t)hs * 2048 + c4;

    float hacc[4][4];
    #pragma unroll
    for (int i = 0; i < 4; i++)
        #pragma unroll
        for (int j = 0; j < 4; j++) hacc[i][j] = 0.f;

    // preload panel 0 into registers
    float4 wreg[4];
    #pragma unroll
    for (int q = 0; q < 4; q++)
        wreg[q] = *(const float4*)(wbase + (size_t)q * 16 * 2048);

    for (int p = 0; p < 32; ++p) {
        __syncthreads();   // Wp free to overwrite (and h1T visible for p=0)
        #pragma unroll
        for (int q = 0; q < 4; q++)
            *(float4*)&Wp[(hs + q * 16) * 64 + c4] = wreg[q];
        __syncthreads();

        // T14: issue next panel's loads now; consumed after compute(p)
        if (p < 31) {
            const float* wsrc = wbase + (p + 1) * 64;
            #pragma unroll
            for (int q = 0; q < 4; q++)
                wreg[q] = *(const float4*)(wsrc + (size_t)q * 16 * 2048);
        }

        int n = p * 2 + n_l;
        // qs values for the fold (global, L1-hot)
        float qv[4];
        #pragma unroll
        for (int i = 0; i < 4; i++)
            qv[i] = qsg[(size_t)(row0 + r0 + i) * 64 + n];

        float c[4][4];
        {
            float bvv[4];
            *(float4*)bvv = *(const float4*)(b12 + n * 32 + e0);
            #pragma unroll
            for (int i = 0; i < 4; i++)
                #pragma unroll
                for (int j = 0; j < 4; j++) c[i][j] = bvv[j];
        }

        #pragma unroll
        for (int k = 0; k < 64; k++) {
            float a[4], wv[4];
            *(float4*)a = *(const float4*)&h1T[k * 64 + r0];
            *(float4*)wv = *(const float4*)&Wp[k * 64 + jcol];
            #pragma unroll
            for (int i = 0; i < 4; i++)
                #pragma unroll
                for (int j = 0; j < 4; j++)
                    c[i][j] = fmaf(a[i], wv[j], c[i][j]);
        }

        #pragma unroll
        for (int i = 0; i < 4; i++)
            #pragma unroll
            for (int j = 0; j < 4; j++)
                hacc[i][j] = fmaf(qv[i], fabsf(c[i][j]), hacc[i][j]);
    }

    // butterfly-reduce over n_l (lane bit 3)
    #pragma unroll
    for (int i = 0; i < 4; i++)
        #pragma unroll
        for (int j = 0; j < 4; j++)
            hacc[i][j] += __shfl_xor(hacc[i][j], 8);

    if (n_l == 0) {
        #pragma unroll
        for (int i = 0; i < 4; i++) {
            float4 v = make_float4(hacc[i][0], hacc[i][1], hacc[i][2], hacc[i][3]);
            *(float4*)&hid[(r0 + i) * 32 + e0] = v;
        }
    }
    __syncthreads();

    // epilogue: 4 threads/row, 8 e each: hidden = elu(hid + b1v); dot w2
    {
        int r = t >> 2, eq = t & 3, he0 = eq * 8;
        int row = row0 + r;
        const float* b1p = b1vg + (size_t)row * 32 + he0;
        const float* w2p = w2g + (size_t)row * 32 + he0;
        float accp = 0.f;
        #pragma unroll
        for (int q = 0; q < 2; q++) {
            float4 hv = *(const float4*)&hid[r * 32 + he0 + q * 4];
            float4 bv = *(const float4*)(b1p + q * 4);
            float4 wv = *(const float4*)(w2p + q * 4);
            float x;
            x = hv.x + bv.x; x = x > 0.f ? x : expm1f(x); accp = fmaf(x, wv.x, accp);
            x = hv.y + bv.y; x = x > 0.f ? x : expm1f(x); accp = fmaf(x, wv.y, accp);
            x = hv.z + bv.z; x = x > 0.f ? x : expm1f(x); accp = fmaf(x, wv.z, accp);
            x = hv.w + bv.w; x = x > 0.f ? x : expm1f(x); accp = fmaf(x, wv.w, accp);
        }
        accp += __shfl_xor(accp, 1);
        accp += __shfl_xor(accp, 2);
        if (eq == 0) out[row] = accp + b2vg[row];
    }
}

// ---------------------------------------------------------------------------
extern "C" void kernel_launch(void* const* d_in, const int* in_sizes, int n_in,
                              void* d_out, int out_size, void* d_ws, size_t ws_size,
                              hipStream_t stream) {
    const float* agent_qs = (const float*)d_in[0];
    const float* obs      = (const float*)d_in[1];
    const int*   agent_mask = (const int*)d_in[2];
    const float* w1_1 = (const float*)d_in[3];
    const float* b1_1 = (const float*)d_in[4];
    const float* w1_2 = (const float*)d_in[5];
    const float* b1_2 = (const float*)d_in[6];
    const float* w2_1 = (const float*)d_in[7];
    const float* b2_1 = (const float*)d_in[8];
    const float* w2_2 = (const float*)d_in[9];
    const float* b2_2 = (const float*)d_in[10];
    const float* wb1  = (const float*)d_in[11];
    const float* bb1  = (const float*)d_in[12];
    const float* wb2_1 = (const float*)d_in[13];
    const float* bb2_1 = (const float*)d_in[14];
    const float* wb2_2 = (const float*)d_in[15];
    const float* bb2_2 = (const float*)d_in[16];

    float* ws = (float*)d_ws;
    float* states = ws;                         // BT*132
    float* h1  = states + (size_t)BT * SP;      // BT*64
    float* t2  = h1  + (size_t)BT * 64;         // BT*64
    float* b1v = t2  + (size_t)BT * 64;         // BT*32
    float* t3  = b1v + (size_t)BT * 32;         // BT*32
    float* w2  = t3  + (size_t)BT * 32;         // BT*32
    float* b2v = w2  + (size_t)BT * 32;         // BT
    float* outp = (float*)d_out;

    k_states<<<BT / 4, 256, 0, stream>>>(obs, agent_mask, states);
    dim3 g1(BT / 128, 2);
    k_mlp1<<<g1, 256, 0, stream>>>(states, w1_1, b1_1, w2_1, b2_1,
                                   wb1, bb1, wb2_1, bb2_1, h1, t2, b1v, t3);
    k_w2<<<BT / 64, 256, 0, stream>>>(t2, t3, w2_2, b2_2, wb2_2, bb2_2, w2, b2v);
    k_main<<<BT / 64, 256, 0, stream>>>(h1, agent_qs, w1_2, b1_2, b1v, w2, b2v, outp);
}